// Round 1
// baseline (1582.857 us; speedup 1.0000x reference)
//
#include <hip/hip_runtime.h>

// ResBlock sparse-conv pipeline, f32 baseline.
// conv = gather(feats[in_idx]) @ W[k]  scatter-add-> out[out_idx]
// entries e in [0, K*P), k = e/P (entries are k-sorted, so W[k] is reused
// across a wave's chunk and held in VGPRs).

__device__ __forceinline__ float lrelu_f(float v) { return v > 0.f ? v : 0.01f * v; }

template<int CIN>
__global__ __launch_bounds__(256) void spconv_f32(
    const float* __restrict__ feats,
    const float* __restrict__ W,      // [K, CIN, 64]
    const int*   __restrict__ iin,    // [E]
    const int*   __restrict__ iout,   // [E]
    int E, int P,
    float* __restrict__ out)          // [n_out, 64], pre-zeroed
{
    constexpr int T = 8;              // entries per wave
    const int lane = threadIdx.x & 63;
    int wid = (blockIdx.x << 2) | (threadIdx.x >> 6);
    wid = __builtin_amdgcn_readfirstlane(wid);
    const int e0 = wid * T;
    if (e0 >= E) return;
    const int cnt = (E - e0 < T) ? (E - e0) : T;

    int kcur = -1;
    float wv[CIN];                    // W[k][:, lane] column in VGPRs

    for (int t = 0; t < cnt; ++t) {
        const int e = e0 + t;
        const int k = e / P;          // uniform; chunk crosses k at most once
        if (k != kcur) {
            kcur = k;
            const float* wp = W + ((size_t)k * CIN) * 64 + lane;
            #pragma unroll
            for (int i = 0; i < CIN; ++i) wv[i] = wp[(size_t)i * 64];
        }
        const int rin  = __builtin_amdgcn_readfirstlane(iin[e]);
        const int rout = __builtin_amdgcn_readfirstlane(iout[e]);
        const float4* f4 = (const float4*)(feats + (size_t)rin * CIN);
        float4 fv[CIN / 4];
        #pragma unroll
        for (int i = 0; i < CIN / 4; ++i) fv[i] = f4[i];   // uniform loads, issued up front
        float a0 = 0.f, a1 = 0.f, a2 = 0.f, a3 = 0.f;
        #pragma unroll
        for (int i = 0; i < CIN / 4; ++i) {
            a0 = fmaf(fv[i].x, wv[4 * i + 0], a0);
            a1 = fmaf(fv[i].y, wv[4 * i + 1], a1);
            a2 = fmaf(fv[i].z, wv[4 * i + 2], a2);
            a3 = fmaf(fv[i].w, wv[4 * i + 3], a3);
        }
        atomicAdd(out + (size_t)rout * 64 + lane, (a0 + a1) + (a2 + a3));
    }
}

// per-channel sum / sumsq of lrelu(A), A is [n, 64]; stats = {sum[64], sumsq[64]} (pre-zeroed)
__global__ __launch_bounds__(256) void bn_stats(
    const float* __restrict__ A, int n, float* __restrict__ stats)
{
    __shared__ float ls[256], lq[256];
    float s = 0.f, q = 0.f;
    const long total = (long)n * 64;
    const long stride = (long)gridDim.x * 256;   // multiple of 64 -> fixed channel class per thread
    for (long i = (long)blockIdx.x * 256 + threadIdx.x; i < total; i += stride) {
        float v = lrelu_f(A[i]);
        s += v; q += v * v;
    }
    ls[threadIdx.x] = s; lq[threadIdx.x] = q;
    __syncthreads();
    if (threadIdx.x < 64) {
        float ss = ls[threadIdx.x] + ls[threadIdx.x + 64] + ls[threadIdx.x + 128] + ls[threadIdx.x + 192];
        float qq = lq[threadIdx.x] + lq[threadIdx.x + 64] + lq[threadIdx.x + 128] + lq[threadIdx.x + 192];
        atomicAdd(&stats[threadIdx.x], ss);
        atomicAdd(&stats[64 + threadIdx.x], qq);
    }
}

// out = bn(lrelu(A)) (+ addsrc), elementwise; safe in-place (outp may alias A)
__global__ __launch_bounds__(256) void bn_apply(
    const float* __restrict__ A, const float* __restrict__ stats,
    const float* __restrict__ gamma, const float* __restrict__ beta,
    const float* __restrict__ addsrc, float* __restrict__ outp, int n)
{
    const int c = threadIdx.x & 63;
    const float inv_n = 1.0f / (float)n;
    const float m  = stats[c] * inv_n;
    const float var = stats[64 + c] * inv_n - m * m;
    const float sc = rsqrtf(var + 1e-5f) * gamma[c];
    const float bb = beta[c] - m * sc;
    const long total = (long)n * 64;
    const long stride = (long)gridDim.x * blockDim.x; // multiple of 64
    for (long i = (long)blockIdx.x * blockDim.x + threadIdx.x; i < total; i += stride) {
        float r = lrelu_f(A[i]) * sc + bb;
        if (addsrc) r += addsrc[i];
        outp[i] = r;
    }
}

extern "C" void kernel_launch(void* const* d_in, const int* in_sizes, int n_in,
                              void* d_out, int out_size, void* d_ws, size_t ws_size,
                              hipStream_t stream)
{
    const float* x   = (const float*)d_in[0];
    const float* W1  = (const float*)d_in[1];
    const float* W12 = (const float*)d_in[2];
    const float* W2  = (const float*)d_in[3];
    const float* W3  = (const float*)d_in[4];
    const float* Wp  = (const float*)d_in[5];
    const float* g0  = (const float*)d_in[6];
    const float* b0  = (const float*)d_in[7];
    const float* g02 = (const float*)d_in[8];
    const float* b02 = (const float*)d_in[9];
    const float* g1  = (const float*)d_in[10];
    const float* b1  = (const float*)d_in[11];
    const float* g2  = (const float*)d_in[12];
    const float* b2  = (const float*)d_in[13];
    const int* rb_a_in  = (const int*)d_in[14];
    const int* rb_a_out = (const int*)d_in[15];
    const int* rb_b_in  = (const int*)d_in[16];
    const int* rb_b_out = (const int*)d_in[17];
    const int* rb_p_in  = (const int*)d_in[18];
    const int* rb_p_out = (const int*)d_in[19];

    const int N  = in_sizes[0] / 32;
    const int M  = out_size / 64 - N;
    const int Ea = in_sizes[14];
    const int Eb = in_sizes[16];
    const int Ep = in_sizes[18];

    float* A     = (float*)d_ws;                 // [N,64] conv accumulator
    float* B     = A + (size_t)N * 64;           // [N,64] shortcut hold
    float* stats = B + (size_t)N * 64;           // 128 floats

    float* resB = (float*)d_out;                 // [M,64]
    float* resA = resB + (size_t)M * 64;         // [N,64]

    const size_t fbytes = (size_t)N * 64 * sizeof(float);
    dim3 blk(256);
    auto cgrid = [](int E) { return dim3((unsigned)((E + 31) / 32)); }; // 4 waves x 8 entries

    // ---- shortcut path: conv1 (3x1, 32->64) -> lrelu/bn -> conv1_2 (1x3, 64->64) -> lrelu/bn
    hipMemsetAsync(A, 0, fbytes, stream);
    spconv_f32<32><<<cgrid(Ea), blk, 0, stream>>>(x, W1, rb_a_in, rb_a_out, Ea, N, A);
    hipMemsetAsync(stats, 0, 128 * sizeof(float), stream);
    bn_stats<<<256, blk, 0, stream>>>(A, N, stats);
    bn_apply<<<512, blk, 0, stream>>>(A, stats, g0, b0, nullptr, B, N);      // B = shortcut1

    hipMemsetAsync(A, 0, fbytes, stream);
    spconv_f32<64><<<cgrid(Eb), blk, 0, stream>>>(B, W12, rb_b_in, rb_b_out, Eb, N, A);
    hipMemsetAsync(stats, 0, 128 * sizeof(float), stream);
    bn_stats<<<256, blk, 0, stream>>>(A, N, stats);
    bn_apply<<<512, blk, 0, stream>>>(A, stats, g02, b02, nullptr, B, N);    // B = shortcut (final)

    // ---- main path: conv2 (1x3, 32->64) -> lrelu/bn (in-place in A)
    hipMemsetAsync(A, 0, fbytes, stream);
    spconv_f32<32><<<cgrid(Eb), blk, 0, stream>>>(x, W2, rb_b_in, rb_b_out, Eb, N, A);
    hipMemsetAsync(stats, 0, 128 * sizeof(float), stream);
    bn_stats<<<256, blk, 0, stream>>>(A, N, stats);
    bn_apply<<<512, blk, 0, stream>>>(A, stats, g1, b1, nullptr, A, N);      // A = resA1

    // ---- conv3 (3x1, 64->64) accumulated directly into d_out's resA region
    hipMemsetAsync(resA, 0, fbytes, stream);
    spconv_f32<64><<<cgrid(Ea), blk, 0, stream>>>(A, W3, rb_a_in, rb_a_out, Ea, N, resA);
    hipMemsetAsync(stats, 0, 128 * sizeof(float), stream);
    bn_stats<<<256, blk, 0, stream>>>(resA, N, stats);
    bn_apply<<<512, blk, 0, stream>>>(resA, stats, g2, b2, B, resA, N);      // resA = bn(lrelu)+shortcut

    // ---- strided pool conv (27 offsets, 64->64) into resB
    hipMemsetAsync(resB, 0, (size_t)M * 64 * sizeof(float), stream);
    spconv_f32<64><<<cgrid(Ep), blk, 0, stream>>>(resA, Wp, rb_p_in, rb_p_out, Ep, N, resB);
}

// Round 2
// 1582.093 us; speedup vs baseline: 1.0005x; 1.0005x over previous
//
#include <hip/hip_runtime.h>

// ResBlock sparse-conv pipeline, bf16-MFMA convs + f32 atomic scatter.
// conv: per offset k (entries [k*P,(k+1)*P) are contiguous), tile 16 entries:
//   A = gathered feats rows [16 x CIN] (bf16), B = W[k] [CIN x 64] (bf16, in VGPRs),
//   C += A@B via mfma_f32_16x16x32_bf16, scatter-add f32 atomics to out[out_idx].

typedef __attribute__((ext_vector_type(8))) short short8;   // 8 x bf16
typedef __attribute__((ext_vector_type(4))) float f32x4;

__device__ __forceinline__ float lrelu_f(float v) { return v > 0.f ? v : 0.01f * v; }
__device__ __forceinline__ short f2bf(float f) {
    unsigned u = __float_as_uint(f);
    unsigned r = (u + 0x7FFFu + ((u >> 16) & 1u)) >> 16;    // RNE
    return (short)r;
}

__global__ __launch_bounds__(256) void f32_to_bf16(
    const float* __restrict__ src, short* __restrict__ dst, int n)
{
    for (int i = blockIdx.x * 256 + threadIdx.x; i < n; i += gridDim.x * 256)
        dst[i] = f2bf(src[i]);
}

// TPW tiles of 16 entries per wave; one k per wave (W[k] held in VGPRs).
template<int CIN>
__global__ __launch_bounds__(256) void spconv_mfma(
    const short* __restrict__ feats,   // [N_in, CIN] bf16
    const short* __restrict__ W,       // [K, CIN, 64] bf16
    const int*   __restrict__ iin,     // [K*P]
    const int*   __restrict__ iout,    // [K*P]
    int P, int tilesPerK, int wavesPerK, int K, int TPW,
    float* __restrict__ out)           // [n_out, 64] f32, pre-zeroed
{
    constexpr int KS = CIN / 32;       // k-steps
    const int lane = threadIdx.x & 63;
    int wid = blockIdx.x * 4 + (threadIdx.x >> 6);
    wid = __builtin_amdgcn_readfirstlane(wid);
    const int k = wid / wavesPerK;
    if (k >= K) return;
    const int wslot = wid % wavesPerK;
    int t0 = wslot * TPW;
    if (t0 >= tilesPerK) return;
    const int t1 = (t0 + TPW < tilesPerK) ? t0 + TPW : tilesPerK;
    const int kBase = k * P;
    const int kEnd  = kBase + P;

    const int col = lane & 15;         // MFMA n / C-col
    const int g   = lane >> 4;         // k-group (regs cover k = g*8 + r)

    // B fragments: B[k][n], lane = col n, regs = k slice. W row-major [CIN][64].
    short8 bf[KS][4];
    const short* wk = W + (size_t)k * CIN * 64;
    #pragma unroll
    for (int kk = 0; kk < KS; ++kk)
        #pragma unroll
        for (int ct = 0; ct < 4; ++ct)
            #pragma unroll
            for (int r = 0; r < 8; ++r)
                bf[kk][ct][r] = wk[(size_t)(kk * 32 + g * 8 + r) * 64 + ct * 16 + col];

    for (int t = t0; t < t1; ++t) {
        const int base = kBase + t * 16;
        int ein = base + col;                       // A row = lane&15
        if (ein >= kEnd) ein = kEnd - 1;
        const int rin = iin[ein];

        short8 af[KS];
        const short* fr = feats + (size_t)rin * CIN + g * 8;
        #pragma unroll
        for (int kk = 0; kk < KS; ++kk)
            af[kk] = *(const short8*)(fr + kk * 32);

        f32x4 acc[4] = {f32x4{0,0,0,0}, f32x4{0,0,0,0}, f32x4{0,0,0,0}, f32x4{0,0,0,0}};
        #pragma unroll
        for (int kk = 0; kk < KS; ++kk)
            #pragma unroll
            for (int ct = 0; ct < 4; ++ct)
                acc[ct] = __builtin_amdgcn_mfma_f32_16x16x32_bf16(af[kk], bf[kk][ct], acc[ct], 0, 0, 0);

        // C/D: row = g*4 + j, col = ct*16 + (lane&15)
        const int rbase = base + g * 4;
        #pragma unroll
        for (int j = 0; j < 4; ++j) {
            const int er = rbase + j;
            if (er < kEnd) {
                const int rout = iout[er];
                float* op = out + (size_t)rout * 64 + col;
                #pragma unroll
                for (int ct = 0; ct < 4; ++ct)
                    atomicAdd(op + ct * 16, acc[ct][j]);
            }
        }
    }
}

// per-channel sum/sumsq of lrelu(A); stats = {sum[64], sumsq[64]} (pre-zeroed)
__global__ __launch_bounds__(256) void bn_stats(
    const float* __restrict__ A, int n, float* __restrict__ stats)
{
    __shared__ float ls[256], lq[256];
    float s = 0.f, q = 0.f;
    const long total = (long)n * 64;
    const long stride = (long)gridDim.x * 256;
    for (long i = (long)blockIdx.x * 256 + threadIdx.x; i < total; i += stride) {
        float v = lrelu_f(A[i]);
        s += v; q += v * v;
    }
    ls[threadIdx.x] = s; lq[threadIdx.x] = q;
    __syncthreads();
    if (threadIdx.x < 64) {
        atomicAdd(&stats[threadIdx.x],
                  ls[threadIdx.x] + ls[threadIdx.x + 64] + ls[threadIdx.x + 128] + ls[threadIdx.x + 192]);
        atomicAdd(&stats[64 + threadIdx.x],
                  lq[threadIdx.x] + lq[threadIdx.x + 64] + lq[threadIdx.x + 128] + lq[threadIdx.x + 192]);
    }
}

// r = bn(lrelu(A)) (+ addsrc); writes f32 and/or bf16 outputs (either may be null)
__global__ __launch_bounds__(256) void bn_apply(
    const float* __restrict__ A, const float* __restrict__ stats,
    const float* __restrict__ gamma, const float* __restrict__ beta,
    const float* __restrict__ addsrc,
    float* __restrict__ out_f32, short* __restrict__ out_bf, int n)
{
    const int c = threadIdx.x & 63;
    const float inv_n = 1.0f / (float)n;
    const float m   = stats[c] * inv_n;
    const float var = stats[64 + c] * inv_n - m * m;
    const float sc  = rsqrtf(var + 1e-5f) * gamma[c];
    const float bb  = beta[c] - m * sc;
    const long total = (long)n * 64;
    const long stride = (long)gridDim.x * blockDim.x;
    for (long i = (long)blockIdx.x * blockDim.x + threadIdx.x; i < total; i += stride) {
        float r = lrelu_f(A[i]) * sc + bb;
        if (addsrc) r += addsrc[i];
        if (out_f32) out_f32[i] = r;
        if (out_bf)  out_bf[i]  = f2bf(r);
    }
}

extern "C" void kernel_launch(void* const* d_in, const int* in_sizes, int n_in,
                              void* d_out, int out_size, void* d_ws, size_t ws_size,
                              hipStream_t stream)
{
    const float* x   = (const float*)d_in[0];
    const float* W1  = (const float*)d_in[1];
    const float* W12 = (const float*)d_in[2];
    const float* W2  = (const float*)d_in[3];
    const float* W3  = (const float*)d_in[4];
    const float* Wp  = (const float*)d_in[5];
    const float* g0  = (const float*)d_in[6];
    const float* b0  = (const float*)d_in[7];
    const float* g02 = (const float*)d_in[8];
    const float* b02 = (const float*)d_in[9];
    const float* g1  = (const float*)d_in[10];
    const float* b1  = (const float*)d_in[11];
    const float* g2  = (const float*)d_in[12];
    const float* b2  = (const float*)d_in[13];
    const int* rb_a_in  = (const int*)d_in[14];
    const int* rb_a_out = (const int*)d_in[15];
    const int* rb_b_in  = (const int*)d_in[16];
    const int* rb_b_out = (const int*)d_in[17];
    const int* rb_p_in  = (const int*)d_in[18];
    const int* rb_p_out = (const int*)d_in[19];

    const int N  = in_sizes[0] / 32;
    const int M  = out_size / 64 - N;
    (void)M;
    const int Ea = in_sizes[14];   // 9*N
    const int Ep = in_sizes[18];   // 27*N
    const int Ka = Ea / N, Kp = Ep / N;   // 9, 27
    const int P  = N;

    // workspace layout (all 16B-aligned)
    float* A     = (float*)d_ws;                        // [N,64] f32 conv accumulator
    float* B     = A + (size_t)N * 64;                  // [N,64] f32 shortcut (final)
    short* x_bf  = (short*)(B + (size_t)N * 64);        // [N,32] bf16
    short* t_bf  = x_bf + (size_t)N * 32;               // [N,64] bf16 (stage input / resA_bf)
    short* W1b   = t_bf + (size_t)N * 64;
    short* W12b  = W1b  + (size_t)9 * 32 * 64;
    short* W2b   = W12b + (size_t)9 * 64 * 64;
    short* W3b   = W2b  + (size_t)9 * 32 * 64;
    short* Wpb   = W3b  + (size_t)9 * 64 * 64;
    float* stats = (float*)(Wpb + (size_t)27 * 64 * 64);

    float* resB = (float*)d_out;                        // [M,64]
    float* resA = resB + (size_t)M * 64;                // [N,64]

    const size_t fbytes = (size_t)N * 64 * sizeof(float);
    const int TPW = 16;
    const int tilesPerK = (P + 15) / 16;
    const int wavesPerK = (tilesPerK + TPW - 1) / TPW;
    auto cblocks = [&](int K) { return dim3((unsigned)((K * wavesPerK + 3) / 4)); };
    dim3 blk(256);

    // dtype converts
    f32_to_bf16<<<256, blk, 0, stream>>>(x, x_bf, N * 32);
    f32_to_bf16<<<8,   blk, 0, stream>>>(W1,  W1b,  9 * 32 * 64);
    f32_to_bf16<<<16,  blk, 0, stream>>>(W12, W12b, 9 * 64 * 64);
    f32_to_bf16<<<8,   blk, 0, stream>>>(W2,  W2b,  9 * 32 * 64);
    f32_to_bf16<<<16,  blk, 0, stream>>>(W3,  W3b,  9 * 64 * 64);
    f32_to_bf16<<<32,  blk, 0, stream>>>(Wp,  Wpb,  27 * 64 * 64);

    // ---- shortcut: conv1 (3x1, 32->64) -> lrelu/bn -> conv1_2 (1x3, 64->64) -> lrelu/bn
    hipMemsetAsync(A, 0, fbytes, stream);
    spconv_mfma<32><<<cblocks(Ka), blk, 0, stream>>>(x_bf, W1b, rb_a_in, rb_a_out, P, tilesPerK, wavesPerK, Ka, TPW, A);
    hipMemsetAsync(stats, 0, 128 * sizeof(float), stream);
    bn_stats<<<256, blk, 0, stream>>>(A, N, stats);
    bn_apply<<<512, blk, 0, stream>>>(A, stats, g0, b0, nullptr, nullptr, t_bf, N);   // t_bf = shortcut1

    hipMemsetAsync(A, 0, fbytes, stream);
    spconv_mfma<64><<<cblocks(Ka), blk, 0, stream>>>(t_bf, W12b, rb_b_in, rb_b_out, P, tilesPerK, wavesPerK, Ka, TPW, A);
    hipMemsetAsync(stats, 0, 128 * sizeof(float), stream);
    bn_stats<<<256, blk, 0, stream>>>(A, N, stats);
    bn_apply<<<512, blk, 0, stream>>>(A, stats, g02, b02, nullptr, B, nullptr, N);    // B = shortcut (f32)

    // ---- main: conv2 (1x3, 32->64) -> lrelu/bn
    hipMemsetAsync(A, 0, fbytes, stream);
    spconv_mfma<32><<<cblocks(Ka), blk, 0, stream>>>(x_bf, W2b, rb_b_in, rb_b_out, P, tilesPerK, wavesPerK, Ka, TPW, A);
    hipMemsetAsync(stats, 0, 128 * sizeof(float), stream);
    bn_stats<<<256, blk, 0, stream>>>(A, N, stats);
    bn_apply<<<512, blk, 0, stream>>>(A, stats, g1, b1, nullptr, nullptr, t_bf, N);   // t_bf = resA1

    // ---- conv3 (3x1, 64->64) -> lrelu/bn + shortcut -> resA (f32 out) + t_bf (bf16)
    hipMemsetAsync(A, 0, fbytes, stream);
    spconv_mfma<64><<<cblocks(Ka), blk, 0, stream>>>(t_bf, W3b, rb_a_in, rb_a_out, P, tilesPerK, wavesPerK, Ka, TPW, A);
    hipMemsetAsync(stats, 0, 128 * sizeof(float), stream);
    bn_stats<<<256, blk, 0, stream>>>(A, N, stats);
    bn_apply<<<512, blk, 0, stream>>>(A, stats, g2, b2, B, resA, t_bf, N);            // resA f32 + bf16 copy

    // ---- strided pool conv (27 offsets, 64->64) -> resB
    hipMemsetAsync(resB, 0, (size_t)M * 64 * sizeof(float), stream);
    spconv_mfma<64><<<cblocks(Kp), blk, 0, stream>>>(t_bf, Wpb, rb_p_in, rb_p_out, P, tilesPerK, wavesPerK, Kp, TPW, resB);
}

// Round 3
// 1488.543 us; speedup vs baseline: 1.0634x; 1.0628x over previous
//
#include <hip/hip_runtime.h>

typedef __attribute__((ext_vector_type(8))) short short8;   // 8 x bf16
typedef __attribute__((ext_vector_type(4))) float f32x4;

__device__ __forceinline__ float lrelu_f(float v) { return v > 0.f ? v : 0.01f * v; }
__device__ __forceinline__ short f2bf(float f) {
    unsigned u = __float_as_uint(f);
    return (short)((u + 0x7FFFu + ((u >> 16) & 1u)) >> 16);    // RNE
}
__device__ __forceinline__ float bf2f(unsigned short h) {
    return __uint_as_float(((unsigned)h) << 16);
}

__global__ __launch_bounds__(256) void f32_to_bf16(
    const float* __restrict__ src, short* __restrict__ dst, int n)
{
    for (int i = blockIdx.x * 256 + threadIdx.x; i < n; i += gridDim.x * 256)
        dst[i] = f2bf(src[i]);
}

// CSR-by-output build: counts pre-zeroed. Fill order nondeterministic (fp sum
// order noise ~1e-6, far under threshold).
__global__ __launch_bounds__(256) void csr_build(
    const int* __restrict__ iout, int E, int* __restrict__ counts,
    int* __restrict__ slots, int cap)
{
    for (int e = blockIdx.x * 256 + threadIdx.x; e < E; e += gridDim.x * 256) {
        int o = iout[e];
        int pos = atomicAdd(&counts[o], 1);
        if (pos < cap) slots[(size_t)o * cap + pos] = e;
    }
}

// Phase 1: per-offset GEMM, y[e - kLo*P][64] bf16, coalesced via in-wave LDS transpose.
template<int CIN>
__global__ __launch_bounds__(256) void spconv_y(
    const short* __restrict__ feats,   // [N_in, CIN] bf16
    const short* __restrict__ W,       // [K, CIN, 64] bf16 (global k index)
    const int*   __restrict__ iin,
    int P, int kLo, int kHi, int tilesPerK, int wavesPerK, int TPW,
    short* __restrict__ y)
{
    constexpr int KS = CIN / 32;
    __shared__ short lds[4][16 * 64];
    const int lane = threadIdx.x & 63;
    const int wib  = threadIdx.x >> 6;
    int wid = blockIdx.x * 4 + wib;
    wid = __builtin_amdgcn_readfirstlane(wid);
    const int k = kLo + wid / wavesPerK;
    if (k >= kHi) return;
    const int wslot = wid % wavesPerK;
    int t0 = wslot * TPW;
    if (t0 >= tilesPerK) return;
    const int t1 = (t0 + TPW < tilesPerK) ? t0 + TPW : tilesPerK;
    const int kBase = k * P, kEnd = kBase + P;
    const int col = lane & 15, g = lane >> 4;

    short8 bf[KS][4];
    const short* wk = W + (size_t)k * CIN * 64;
    #pragma unroll
    for (int kk = 0; kk < KS; ++kk)
        #pragma unroll
        for (int ct = 0; ct < 4; ++ct)
            #pragma unroll
            for (int r = 0; r < 8; ++r)
                bf[kk][ct][r] = wk[(size_t)(kk * 32 + g * 8 + r) * 64 + ct * 16 + col];

    short* my = lds[wib];
    const size_t eOff = (size_t)kLo * P;
    const int row = lane >> 2;          // store-side: 4 lanes per y row
    const int seg = lane & 3;

    for (int t = t0; t < t1; ++t) {
        const int base = kBase + t * 16;
        int ein = base + col;
        if (ein >= kEnd) ein = kEnd - 1;
        const int rin = iin[ein];
        short8 af[KS];
        const short* fr = feats + (size_t)rin * CIN + g * 8;
        #pragma unroll
        for (int kk = 0; kk < KS; ++kk)
            af[kk] = *(const short8*)(fr + kk * 32);

        f32x4 acc[4] = {f32x4{0,0,0,0}, f32x4{0,0,0,0}, f32x4{0,0,0,0}, f32x4{0,0,0,0}};
        #pragma unroll
        for (int kk = 0; kk < KS; ++kk)
            #pragma unroll
            for (int ct = 0; ct < 4; ++ct)
                acc[ct] = __builtin_amdgcn_mfma_f32_16x16x32_bf16(af[kk], bf[kk][ct], acc[ct], 0, 0, 0);

        // C row = g*4+j, col = ct*16+col  ->  LDS row-major [16][64]
        #pragma unroll
        for (int ct = 0; ct < 4; ++ct)
            #pragma unroll
            for (int j = 0; j < 4; ++j)
                my[(g * 4 + j) * 64 + ct * 16 + col] = f2bf(acc[ct][j]);
        // in-wave transpose readback (lockstep; compiler inserts lgkmcnt)
        short8 v0 = *(const short8*)&my[lane * 16];
        short8 v1 = *(const short8*)&my[lane * 16 + 8];
        if (base + row < kEnd) {
            short* dst = y + (size_t)(base + row - eOff) * 64 + seg * 16;
            *(short8*)dst = v0;
            *(short8*)(dst + 8) = v1;
        }
    }
}

// Phase 2: out-centric segment reduce. wave = one output row, lane = channel.
__global__ __launch_bounds__(256) void reduce_rows(
    const short* __restrict__ y, const int* __restrict__ counts,
    const int* __restrict__ slots, int cap, int eLo, int eHi,
    float* __restrict__ out, int nRows, int accumulate)
{
    const int lane = threadIdx.x & 63;
    const int row = blockIdx.x * 4 + (threadIdx.x >> 6);
    if (row >= nRows) return;
    int cnt = counts[row]; if (cnt > cap) cnt = cap;
    const int* sl = slots + (size_t)row * cap;
    const unsigned short* yu = (const unsigned short*)y;
    float a0 = 0.f, a1 = 0.f, a2 = 0.f, a3 = 0.f;
    int i = 0;
    for (; i + 4 <= cnt; i += 4) {
        int e0 = sl[i], e1 = sl[i+1], e2 = sl[i+2], e3 = sl[i+3];
        if (e0 >= eLo && e0 < eHi) a0 += bf2f(yu[(size_t)(e0 - eLo) * 64 + lane]);
        if (e1 >= eLo && e1 < eHi) a1 += bf2f(yu[(size_t)(e1 - eLo) * 64 + lane]);
        if (e2 >= eLo && e2 < eHi) a2 += bf2f(yu[(size_t)(e2 - eLo) * 64 + lane]);
        if (e3 >= eLo && e3 < eHi) a3 += bf2f(yu[(size_t)(e3 - eLo) * 64 + lane]);
    }
    for (; i < cnt; ++i) {
        int e = sl[i];
        if (e >= eLo && e < eHi) a0 += bf2f(yu[(size_t)(e - eLo) * 64 + lane]);
    }
    float s = (a0 + a1) + (a2 + a3);
    float* op = out + (size_t)row * 64 + lane;
    if (accumulate) s += *op;
    *op = s;
}

// ---------------- fallback (round-2 atomic path) ----------------
template<int CIN>
__global__ __launch_bounds__(256) void spconv_mfma(
    const short* __restrict__ feats, const short* __restrict__ W,
    const int* __restrict__ iin, const int* __restrict__ iout,
    int P, int tilesPerK, int wavesPerK, int K, int TPW,
    float* __restrict__ out)
{
    constexpr int KS = CIN / 32;
    const int lane = threadIdx.x & 63;
    int wid = blockIdx.x * 4 + (threadIdx.x >> 6);
    wid = __builtin_amdgcn_readfirstlane(wid);
    const int k = wid / wavesPerK;
    if (k >= K) return;
    const int wslot = wid % wavesPerK;
    int t0 = wslot * TPW;
    if (t0 >= tilesPerK) return;
    const int t1 = (t0 + TPW < tilesPerK) ? t0 + TPW : tilesPerK;
    const int kBase = k * P, kEnd = kBase + P;
    const int col = lane & 15, g = lane >> 4;
    short8 bf[KS][4];
    const short* wk = W + (size_t)k * CIN * 64;
    #pragma unroll
    for (int kk = 0; kk < KS; ++kk)
        #pragma unroll
        for (int ct = 0; ct < 4; ++ct)
            #pragma unroll
            for (int r = 0; r < 8; ++r)
                bf[kk][ct][r] = wk[(size_t)(kk * 32 + g * 8 + r) * 64 + ct * 16 + col];
    for (int t = t0; t < t1; ++t) {
        const int base = kBase + t * 16;
        int ein = base + col;
        if (ein >= kEnd) ein = kEnd - 1;
        const int rin = iin[ein];
        short8 af[KS];
        const short* fr = feats + (size_t)rin * CIN + g * 8;
        #pragma unroll
        for (int kk = 0; kk < KS; ++kk)
            af[kk] = *(const short8*)(fr + kk * 32);
        f32x4 acc[4] = {f32x4{0,0,0,0}, f32x4{0,0,0,0}, f32x4{0,0,0,0}, f32x4{0,0,0,0}};
        #pragma unroll
        for (int kk = 0; kk < KS; ++kk)
            #pragma unroll
            for (int ct = 0; ct < 4; ++ct)
                acc[ct] = __builtin_amdgcn_mfma_f32_16x16x32_bf16(af[kk], bf[kk][ct], acc[ct], 0, 0, 0);
        const int rbase = base + g * 4;
        #pragma unroll
        for (int j = 0; j < 4; ++j) {
            const int er = rbase + j;
            if (er < kEnd) {
                const int rout = iout[er];
                float* op = out + (size_t)rout * 64 + col;
                #pragma unroll
                for (int ct = 0; ct < 4; ++ct)
                    atomicAdd(op + ct * 16, acc[ct][j]);
            }
        }
    }
}

__global__ __launch_bounds__(256) void bn_stats(
    const float* __restrict__ A, int n, float* __restrict__ stats)
{
    __shared__ float ls[256], lq[256];
    float s = 0.f, q = 0.f;
    const long total = (long)n * 64;
    const long stride = (long)gridDim.x * 256;
    for (long i = (long)blockIdx.x * 256 + threadIdx.x; i < total; i += stride) {
        float v = lrelu_f(A[i]);
        s += v; q += v * v;
    }
    ls[threadIdx.x] = s; lq[threadIdx.x] = q;
    __syncthreads();
    if (threadIdx.x < 64) {
        atomicAdd(&stats[threadIdx.x],
                  ls[threadIdx.x] + ls[threadIdx.x + 64] + ls[threadIdx.x + 128] + ls[threadIdx.x + 192]);
        atomicAdd(&stats[64 + threadIdx.x],
                  lq[threadIdx.x] + lq[threadIdx.x + 64] + lq[threadIdx.x + 128] + lq[threadIdx.x + 192]);
    }
}

__global__ __launch_bounds__(256) void bn_apply(
    const float* __restrict__ A, const float* __restrict__ stats,
    const float* __restrict__ gamma, const float* __restrict__ beta,
    const float* __restrict__ addsrc,
    float* __restrict__ out_f32, short* __restrict__ out_bf, int n)
{
    const int c = threadIdx.x & 63;
    const float inv_n = 1.0f / (float)n;
    const float m   = stats[c] * inv_n;
    const float var = stats[64 + c] * inv_n - m * m;
    const float sc  = rsqrtf(var + 1e-5f) * gamma[c];
    const float bb  = beta[c] - m * sc;
    const long total = (long)n * 64;
    const long stride = (long)gridDim.x * blockDim.x;
    for (long i = (long)blockIdx.x * blockDim.x + threadIdx.x; i < total; i += stride) {
        float r = lrelu_f(A[i]) * sc + bb;
        if (addsrc) r += addsrc[i];
        if (out_f32) out_f32[i] = r;
        if (out_bf)  out_bf[i]  = f2bf(r);
    }
}

extern "C" void kernel_launch(void* const* d_in, const int* in_sizes, int n_in,
                              void* d_out, int out_size, void* d_ws, size_t ws_size,
                              hipStream_t stream)
{
    const float* x   = (const float*)d_in[0];
    const float* W1  = (const float*)d_in[1];
    const float* W12 = (const float*)d_in[2];
    const float* W2  = (const float*)d_in[3];
    const float* W3  = (const float*)d_in[4];
    const float* Wp  = (const float*)d_in[5];
    const float* g0  = (const float*)d_in[6];
    const float* b0  = (const float*)d_in[7];
    const float* g02 = (const float*)d_in[8];
    const float* b02 = (const float*)d_in[9];
    const float* g1  = (const float*)d_in[10];
    const float* b1  = (const float*)d_in[11];
    const float* g2  = (const float*)d_in[12];
    const float* b2  = (const float*)d_in[13];
    const int* rb_a_in  = (const int*)d_in[14];
    const int* rb_a_out = (const int*)d_in[15];
    const int* rb_b_in  = (const int*)d_in[16];
    const int* rb_b_out = (const int*)d_in[17];
    const int* rb_p_in  = (const int*)d_in[18];
    const int* rb_p_out = (const int*)d_in[19];

    const int N  = in_sizes[0] / 32;
    const int M  = out_size / 64 - N;
    const int Ea = in_sizes[14];                 // 9*N
    const int Eb = in_sizes[16];                 // 9*N
    const int Ep = in_sizes[18];                 // 27*N
    const int Ka = Ea / N, Kp = Ep / N;          // 9, 27
    const int P  = N;

    float* resB = (float*)d_out;
    float* resA = resB + (size_t)M * 64;

    const int CAP_AB = 40, CAP_P = 224;

    // ---- workspace layout (new path) ----
    size_t off = 0;
    auto take = [&](size_t bytes) { size_t o = off; off += (bytes + 255) & ~(size_t)255; return o; };
    char* base = (char*)d_ws;
    size_t oA   = take((size_t)N * 64 * 4);
    size_t oB   = take((size_t)N * 64 * 4);
    size_t oxb  = take((size_t)N * 32 * 2);
    size_t otb  = take((size_t)N * 64 * 2);
    size_t oW1  = take((size_t)9 * 32 * 64 * 2);
    size_t oW12 = take((size_t)9 * 64 * 64 * 2);
    size_t oW2  = take((size_t)9 * 32 * 64 * 2);
    size_t oW3  = take((size_t)9 * 64 * 64 * 2);
    size_t oWp  = take((size_t)27 * 64 * 64 * 2);
    size_t oSt  = take(128 * 4);
    size_t oCa  = take((size_t)N * 4);
    size_t oCb  = take((size_t)N * 4);
    size_t oCp  = take((size_t)M * 4);
    size_t oSa  = take((size_t)N * CAP_AB * 4);
    size_t oSb  = take((size_t)N * CAP_AB * 4);
    size_t oSp  = take((size_t)M * CAP_P * 4);
    size_t oY   = take((size_t)Ka * P * 64 * 2);   // y buffer, reused (max 9*P rows)
    const bool fits = (off <= ws_size);

    float* A     = (float*)(base + oA);
    float* B     = (float*)(base + oB);
    short* x_bf  = (short*)(base + oxb);
    short* t_bf  = (short*)(base + otb);
    short* W1b   = (short*)(base + oW1);
    short* W12b  = (short*)(base + oW12);
    short* W2b   = (short*)(base + oW2);
    short* W3b   = (short*)(base + oW3);
    short* Wpb   = (short*)(base + oWp);
    float* stats = (float*)(base + oSt);
    int*   Ca    = (int*)(base + oCa);
    int*   Cb    = (int*)(base + oCb);
    int*   Cp    = (int*)(base + oCp);
    int*   Sa    = (int*)(base + oSa);
    int*   Sb    = (int*)(base + oSb);
    int*   Sp    = (int*)(base + oSp);
    short* yb    = (short*)(base + oY);

    dim3 blk(256);
    const int tilesPerK = (P + 15) / 16;

    // dtype converts (both paths)
    f32_to_bf16<<<256, blk, 0, stream>>>(x, x_bf, N * 32);
    f32_to_bf16<<<8,   blk, 0, stream>>>(W1,  W1b,  9 * 32 * 64);
    f32_to_bf16<<<16,  blk, 0, stream>>>(W12, W12b, 9 * 64 * 64);
    f32_to_bf16<<<8,   blk, 0, stream>>>(W2,  W2b,  9 * 32 * 64);
    f32_to_bf16<<<16,  blk, 0, stream>>>(W3,  W3b,  9 * 64 * 64);
    f32_to_bf16<<<32,  blk, 0, stream>>>(Wp,  Wpb,  27 * 64 * 64);

    if (fits) {
        const int TPW = 4;
        const int wavesPerK = (tilesPerK + TPW - 1) / TPW;
        auto gWaves = [&](int nk) { return dim3((unsigned)((nk * wavesPerK + 3) / 4)); };
        auto gRows  = [&](int nr) { return dim3((unsigned)((nr + 3) / 4)); };

        // CSR builds
        hipMemsetAsync(Ca, 0, (size_t)N * 4, stream);
        hipMemsetAsync(Cb, 0, (size_t)N * 4, stream);
        hipMemsetAsync(Cp, 0, (size_t)M * 4, stream);
        csr_build<<<2048, blk, 0, stream>>>(rb_a_out, Ea, Ca, Sa, CAP_AB);
        csr_build<<<2048, blk, 0, stream>>>(rb_b_out, Eb, Cb, Sb, CAP_AB);
        csr_build<<<2048, blk, 0, stream>>>(rb_p_out, Ep, Cp, Sp, CAP_P);

        // conv1 (rb_a, 32->64) -> A ; bn -> t_bf
        spconv_y<32><<<gWaves(Ka), blk, 0, stream>>>(x_bf, W1b, rb_a_in, P, 0, Ka, tilesPerK, wavesPerK, TPW, yb);
        reduce_rows<<<gRows(N), blk, 0, stream>>>(yb, Ca, Sa, CAP_AB, 0, Ea, A, N, 0);
        hipMemsetAsync(stats, 0, 512, stream);
        bn_stats<<<256, blk, 0, stream>>>(A, N, stats);
        bn_apply<<<512, blk, 0, stream>>>(A, stats, g0, b0, nullptr, nullptr, t_bf, N);

        // conv1_2 (rb_b, 64->64) -> A ; bn -> B (f32)
        spconv_y<64><<<gWaves(Ka), blk, 0, stream>>>(t_bf, W12b, rb_b_in, P, 0, Ka, tilesPerK, wavesPerK, TPW, yb);
        reduce_rows<<<gRows(N), blk, 0, stream>>>(yb, Cb, Sb, CAP_AB, 0, Eb, A, N, 0);
        hipMemsetAsync(stats, 0, 512, stream);
        bn_stats<<<256, blk, 0, stream>>>(A, N, stats);
        bn_apply<<<512, blk, 0, stream>>>(A, stats, g02, b02, nullptr, B, nullptr, N);

        // conv2 (rb_b, 32->64) -> A ; bn -> t_bf
        spconv_y<32><<<gWaves(Ka), blk, 0, stream>>>(x_bf, W2b, rb_b_in, P, 0, Ka, tilesPerK, wavesPerK, TPW, yb);
        reduce_rows<<<gRows(N), blk, 0, stream>>>(yb, Cb, Sb, CAP_AB, 0, Eb, A, N, 0);
        hipMemsetAsync(stats, 0, 512, stream);
        bn_stats<<<256, blk, 0, stream>>>(A, N, stats);
        bn_apply<<<512, blk, 0, stream>>>(A, stats, g1, b1, nullptr, nullptr, t_bf, N);

        // conv3 (rb_a, 64->64) -> A ; bn + shortcut -> resA (f32) + t_bf (bf16)
        spconv_y<64><<<gWaves(Ka), blk, 0, stream>>>(t_bf, W3b, rb_a_in, P, 0, Ka, tilesPerK, wavesPerK, TPW, yb);
        reduce_rows<<<gRows(N), blk, 0, stream>>>(yb, Ca, Sa, CAP_AB, 0, Ea, A, N, 0);
        hipMemsetAsync(stats, 0, 512, stream);
        bn_stats<<<256, blk, 0, stream>>>(A, N, stats);
        bn_apply<<<512, blk, 0, stream>>>(A, stats, g2, b2, B, resA, t_bf, N);

        // pool conv (rb_p, 64->64), k-chunked: 7+7+7+6
        const int kc[5] = {0, 7, 14, 21, Kp};
        for (int c = 0; c < 4; ++c) {
            const int kLo = kc[c], kHi = kc[c + 1];
            spconv_y<64><<<gWaves(kHi - kLo), blk, 0, stream>>>(t_bf, Wpb, rb_p_in, P, kLo, kHi, tilesPerK, wavesPerK, TPW, yb);
            reduce_rows<<<gRows(M), blk, 0, stream>>>(yb, Cp, Sp, CAP_P, kLo * P, kHi * P, resB, M, c > 0);
        }
    } else {
        // -------- fallback: round-2 atomic path (ws-lean) --------
        const int TPW = 16;
        const int wavesPerK = (tilesPerK + TPW - 1) / TPW;
        auto cblocks = [&](int K) { return dim3((unsigned)((K * wavesPerK + 3) / 4)); };
        const size_t fbytes = (size_t)N * 64 * sizeof(float);

        hipMemsetAsync(A, 0, fbytes, stream);
        spconv_mfma<32><<<cblocks(Ka), blk, 0, stream>>>(x_bf, W1b, rb_a_in, rb_a_out, P, tilesPerK, wavesPerK, Ka, TPW, A);
        hipMemsetAsync(stats, 0, 512, stream);
        bn_stats<<<256, blk, 0, stream>>>(A, N, stats);
        bn_apply<<<512, blk, 0, stream>>>(A, stats, g0, b0, nullptr, nullptr, t_bf, N);

        hipMemsetAsync(A, 0, fbytes, stream);
        spconv_mfma<64><<<cblocks(Ka), blk, 0, stream>>>(t_bf, W12b, rb_b_in, rb_b_out, P, tilesPerK, wavesPerK, Ka, TPW, A);
        hipMemsetAsync(stats, 0, 512, stream);
        bn_stats<<<256, blk, 0, stream>>>(A, N, stats);
        bn_apply<<<512, blk, 0, stream>>>(A, stats, g02, b02, nullptr, B, nullptr, N);

        hipMemsetAsync(A, 0, fbytes, stream);
        spconv_mfma<32><<<cblocks(Ka), blk, 0, stream>>>(x_bf, W2b, rb_b_in, rb_b_out, P, tilesPerK, wavesPerK, Ka, TPW, A);
        hipMemsetAsync(stats, 0, 512, stream);
        bn_stats<<<256, blk, 0, stream>>>(A, N, stats);
        bn_apply<<<512, blk, 0, stream>>>(A, stats, g1, b1, nullptr, nullptr, t_bf, N);

        hipMemsetAsync(resA, 0, fbytes, stream);
        spconv_mfma<64><<<cblocks(Ka), blk, 0, stream>>>(t_bf, W3b, rb_a_in, rb_a_out, P, tilesPerK, wavesPerK, Ka, TPW, resA);
        hipMemsetAsync(stats, 0, 512, stream);
        bn_stats<<<256, blk, 0, stream>>>(resA, N, stats);
        bn_apply<<<512, blk, 0, stream>>>(resA, stats, g2, b2, B, resA, t_bf, N);

        hipMemsetAsync(resB, 0, (size_t)M * 64 * sizeof(float), stream);
        spconv_mfma<64><<<cblocks(Kp), blk, 0, stream>>>(t_bf, Wpb, rb_p_in, rb_p_out, P, tilesPerK, wavesPerK, Kp, TPW, resB);
    }
}